// Round 4
// baseline (384.655 us; speedup 1.0000x reference)
//
#include <hip/hip_runtime.h>
#include <stdint.h>

#define NUM_EXPERT 8
#define IN_FEAT 1024
#define OUT_FEAT 4096
#define N_TOKENS 4096

#define BM 128
#define BN 128
#define BK 32
#define NT (IN_FEAT / BK)     // 32 K-steps
#define MAX_ROW_TILES 40      // worst-case sum_e ceil(cnt_e/128)

typedef __attribute__((ext_vector_type(8))) short short8;   // 8 x bf16 bits
typedef __attribute__((ext_vector_type(4))) float f32x4;

__device__ __forceinline__ unsigned int cvtpk(float lo, float hi) {
    // 2 fp32 -> 2 bf16 (RNE), packed: lo -> bits[15:0], hi -> bits[31:16]
    unsigned int r;
    asm("v_cvt_pk_bf16_f32 %0, %1, %2" : "=v"(r) : "v"(lo), "v"(hi));
    return r;
}

__device__ __forceinline__ uint4 cvt8(float4 v0, float4 v1) {
    // 8 fp32 -> 8 bf16 (16 B), ready for one ds_write_b128
    uint4 r;
    r.x = cvtpk(v0.x, v0.y);
    r.y = cvtpk(v0.z, v0.w);
    r.z = cvtpk(v1.x, v1.y);
    r.w = cvtpk(v1.z, v1.w);
    return r;
}

// Raw barrier: LDS-drain + visibility WITHOUT draining vmcnt, so global
// loads stay in flight across it. sched_barrier(0) pins LDS reads from
// migrating above the s_barrier.
#define LDS_BARRIER()                                                   \
    do {                                                                \
        asm volatile("s_waitcnt lgkmcnt(0)" ::: "memory");              \
        __builtin_amdgcn_s_barrier();                                   \
        __builtin_amdgcn_sched_barrier(0);                              \
    } while (0)

// ---------------- Kernel 1: gate sort only (1 block) -------------------------
// meta layout (int): [0..7]=cnt, [8..15]=off, [16..16+4096)=perm
__global__ __launch_bounds__(256)
void moe_sort(const int* __restrict__ gate, int* __restrict__ meta) {
    __shared__ int cnt[NUM_EXPERT];
    __shared__ int off[NUM_EXPERT];
    __shared__ int wsum[4];
    const int tid  = threadIdx.x;
    const int lane = tid & 63;
    const int wave = tid >> 6;

    int gv[16];
    const int4* gp = (const int4*)(gate + tid * 16);
#pragma unroll
    for (int i = 0; i < 4; ++i) {
        int4 v = gp[i];
        gv[i * 4 + 0] = v.x; gv[i * 4 + 1] = v.y;
        gv[i * 4 + 2] = v.z; gv[i * 4 + 3] = v.w;
    }
    int lc[NUM_EXPERT];
#pragma unroll
    for (int e = 0; e < NUM_EXPERT; ++e) {
        int c = 0;
#pragma unroll
        for (int j = 0; j < 16; ++j) c += (gv[j] == e) ? 1 : 0;
        lc[e] = c;
    }
    if (tid < NUM_EXPERT) cnt[tid] = 0;
    __syncthreads();
#pragma unroll
    for (int e = 0; e < NUM_EXPERT; ++e) {
        int c = lc[e];
#pragma unroll
        for (int d = 32; d > 0; d >>= 1) c += __shfl_down(c, d);
        if (lane == 0 && c) atomicAdd(&cnt[e], c);
    }
    __syncthreads();
    if (tid == 0) {
        int a = 0;
#pragma unroll
        for (int e = 0; e < NUM_EXPERT; ++e) { off[e] = a; a += cnt[e]; }
    }
    __syncthreads();
    if (tid < NUM_EXPERT) { meta[tid] = cnt[tid]; meta[8 + tid] = off[tid]; }

    int* perm = meta + 16;
#pragma unroll
    for (int e = 0; e < NUM_EXPERT; ++e) {
        int c_t = lc[e];
        int inc = c_t;
#pragma unroll
        for (int d = 1; d < 64; d <<= 1) {
            int t = __shfl_up(inc, d);
            if (lane >= d) inc += t;
        }
        if (lane == 63) wsum[wave] = inc;
        __syncthreads();
        int base = off[e];
#pragma unroll
        for (int w = 0; w < 4; ++w) if (w < wave) base += wsum[w];
        int rank = base + inc - c_t;
#pragma unroll
        for (int j = 0; j < 16; ++j) {
            if (gv[j] == e) { perm[rank] = tid * 16 + j; rank++; }
        }
        __syncthreads();
    }
}

// ---------------- Kernel 2: fused fp32->bf16 grouped GEMM, BK=32 -------------
// C[tok][n] = sum_k inp[tok][k] * W[e][n][k]
// 32 KB LDS double-buffer (up to 5 blocks/CU -> TLP latency hiding, the R3
// fix: 64 KB LDS capped us at 2 waves/SIMD, fundamentally latency-bound).
// LDS layout is chunk-major [kchunk][row][16B]: sequential ds_writes,
// 2-way-aliased (free) ds_reads -- no swizzle needed.
//   iter t:  ds_read frags(buf[cur])
//            -> cvt regs(tile t+1) [counted vmcnt] -> ds_write buf[cur^1]
//            -> issue global loads(tile t+2)  [in flight across barrier]
//            -> MFMA -> lgkm-drain + raw barrier
__global__ __launch_bounds__(256)
void moe_gemm_fused(const float* __restrict__ inp,
                    const float* __restrict__ weight,
                    const int* __restrict__ meta,
                    float* __restrict__ out) {
    // per buffer: A 8 KB + B 8 KB; 2 buffers = 32768 B total
    __shared__ __align__(16) unsigned short Ls[2][8192];

    const int* cnt  = meta;
    const int* off  = meta + 8;
    const int* perm = meta + 16;

    // ---- map blockIdx.y -> (expert, local row-tile); block-uniform ----
    int local = blockIdx.y;
    int e = -1, grp_cnt = 0, grp_off = 0;
#pragma unroll
    for (int i = 0; i < NUM_EXPERT; ++i) {
        int c = cnt[i];
        int t = (c + BM - 1) >> 7;
        if (e < 0) {
            if (local < t) { e = i; grp_cnt = c; grp_off = off[i]; }
            else           local -= t;
        }
    }
    if (e < 0) return;

    const int n0   = blockIdx.x * BN;
    const int row0 = local * BM;
    int vcnt = grp_cnt - row0; if (vcnt > BM) vcnt = BM;

    const int tid  = threadIdx.x;
    const int lane = tid & 63;
    const int wave = tid >> 6;

    // ---- staging: chunk = 8 k-elems = 32 B fp32 global = 16 B bf16 LDS.
    // A tile = 128 rows x 4 kchunks = 512 chunks; thread owns c = i*256+tid,
    // i in {0,1}: row = c & 127, kc = c >> 7.
    // LDS addr (chunk-major) = kc*2048 + row*16; B region at +8192.
    const char* ag[2]; const char* bg[2];
    int lofs[2];
    const char* inp_b = (const char*)inp;
    const char* w_b   = (const char*)weight + (size_t)e * (size_t)(OUT_FEAT * IN_FEAT) * 4;
#pragma unroll
    for (int i = 0; i < 2; ++i) {
        int c   = i * 256 + tid;
        int row = c & 127;
        int kc  = c >> 7;
        int p   = row0 + row; if (p > grp_cnt - 1) p = grp_cnt - 1;  // clamp tail
        int tok = perm[grp_off + p];
        ag[i] = inp_b + (size_t)tok * (IN_FEAT * 4) + kc * 32;
        bg[i] = w_b   + (size_t)(n0 + row) * (IN_FEAT * 4) + kc * 32;
        lofs[i] = kc * 2048 + row * 16;
    }

    // ---- fragment LDS offsets: lane(lcol,quad) reads row (wm|wn)+t*16+lcol,
    // k-chunk = quad  ->  addr = quad*2048 + row*16 ----
    const int wm   = (wave & 1) * 64;
    const int wn   = (wave >> 1) * 64;
    const int lcol = lane & 15;
    const int quad = lane >> 4;

    int aoff[4], boff[4];
#pragma unroll
    for (int t = 0; t < 4; ++t) {
        aoff[t] = quad * 2048 + (wm + t * 16 + lcol) * 16;
        boff[t] = 8192 + quad * 2048 + (wn + t * 16 + lcol) * 16;
    }

    const f32x4 vzero = {0.f, 0.f, 0.f, 0.f};
    f32x4 acc[4][4];
#pragma unroll
    for (int i = 0; i < 4; ++i)
#pragma unroll
        for (int j = 0; j < 4; ++j) acc[i][j] = vzero;

    char* L = (char*)Ls;

    // ---- pipeline registers: one tile (A+B) in flight = 8 float4 ----
    float4 raf[2][2], rbf[2][2];

#define LOAD_TILE()                                                     \
    do {                                                                \
        _Pragma("unroll")                                               \
        for (int i = 0; i < 2; ++i) {                                   \
            raf[i][0] = *(const float4*)(ag[i]);                        \
            raf[i][1] = *(const float4*)(ag[i] + 16);                   \
            ag[i] += BK * 4;                                            \
            rbf[i][0] = *(const float4*)(bg[i]);                        \
            rbf[i][1] = *(const float4*)(bg[i] + 16);                   \
            bg[i] += BK * 4;                                            \
        }                                                               \
    } while (0)

#define WRITE_TILE(b)                                                   \
    do {                                                                \
        _Pragma("unroll")                                               \
        for (int i = 0; i < 2; ++i) {                                   \
            *(uint4*)(L + (b) * 16384 + lofs[i])        = cvt8(raf[i][0], raf[i][1]); \
            *(uint4*)(L + (b) * 16384 + 8192 + lofs[i]) = cvt8(rbf[i][0], rbf[i][1]); \
        }                                                               \
    } while (0)

    // prologue: tile 0 -> buf0; tile 1 loads in flight (NOT drained by barrier)
    LOAD_TILE();
    WRITE_TILE(0);
    LOAD_TILE();
    LDS_BARRIER();

    int cur = 0;
    for (int t = 0; t < NT; ++t) {
        const char* base = L + cur * 16384;

        short8 af[4], bf[4];
#pragma unroll
        for (int im = 0; im < 4; ++im) af[im] = *(const short8*)(base + aoff[im]);
#pragma unroll
        for (int jn = 0; jn < 4; ++jn) bf[jn] = *(const short8*)(base + boff[jn]);

        if (t + 1 < NT) {
            WRITE_TILE(cur ^ 1);             // counted vmcnt wait; cvt; ds_write
            if (t + 2 < NT) LOAD_TILE();     // issue; stays in flight across barrier
        }

        __builtin_amdgcn_s_setprio(1);
#pragma unroll
        for (int im = 0; im < 4; ++im)
#pragma unroll
            for (int jn = 0; jn < 4; ++jn)
                acc[im][jn] = __builtin_amdgcn_mfma_f32_16x16x32_bf16(
                    af[im], bf[jn], acc[im][jn], 0, 0, 0);
        __builtin_amdgcn_s_setprio(0);

        LDS_BARRIER();
        cur ^= 1;
    }

#undef LOAD_TILE
#undef WRITE_TILE

    // ---- epilogue: C/D layout col=lane&15, row=quad*4+reg; fp32 scatter ----
#pragma unroll
    for (int im = 0; im < 4; ++im) {
#pragma unroll
        for (int reg = 0; reg < 4; ++reg) {
            int r = wm + im * 16 + quad * 4 + reg;
            if (r < vcnt) {
                int tok = perm[grp_off + row0 + r];
                float* orow = out + (size_t)tok * OUT_FEAT + (n0 + wn + lcol);
#pragma unroll
                for (int jn = 0; jn < 4; ++jn)
                    orow[jn * 16] = acc[im][jn][reg];
            }
        }
    }
}

extern "C" void kernel_launch(void* const* d_in, const int* in_sizes, int n_in,
                              void* d_out, int out_size, void* d_ws, size_t ws_size,
                              hipStream_t stream) {
    const float* inp    = (const float*)d_in[0];   // fp32 [4096,1024]
    const int*   gate   = (const int*)d_in[1];     // int32 [4096]
    const float* weight = (const float*)d_in[2];   // fp32 [8,4096,1024]
    float*       out    = (float*)d_out;           // fp32 [4096,4096]
    (void)in_sizes; (void)n_in; (void)out_size; (void)ws_size;

    int* meta = (int*)d_ws;    // cnt/off/perm (~16.5 KB)

    moe_sort<<<1, 256, 0, stream>>>(gate, meta);
    dim3 grid(OUT_FEAT / BN, MAX_ROW_TILES);
    moe_gemm_fused<<<grid, 256, 0, stream>>>(inp, weight, meta, out);
}

// Round 5
// 285.275 us; speedup vs baseline: 1.3484x; 1.3484x over previous
//
#include <hip/hip_runtime.h>
#include <stdint.h>

#define NUM_EXPERT 8
#define IN_FEAT 1024
#define OUT_FEAT 4096
#define N_TOKENS 4096

#define BM 128
#define BN 128
#define BK 64
#define MAX_ROW_TILES 40      // worst-case sum_e ceil(cnt_e/128)

// prep grid: 256 blocks convert inp, 2048 convert weight, last block sorts
#define CONV_BLKS_INP 256
#define CONV_BLKS_W   2048
#define PREP_BLKS (CONV_BLKS_INP + CONV_BLKS_W + 1)   // 2305

typedef __attribute__((ext_vector_type(8))) short short8;   // 8 x bf16 bits
typedef __attribute__((ext_vector_type(4))) float f32x4;

__device__ __forceinline__ void async_cp16(const void* g, void* l) {
    __builtin_amdgcn_global_load_lds(
        (const __attribute__((address_space(1))) void*)g,
        (__attribute__((address_space(3))) void*)l, 16, 0, 0);
}

__device__ __forceinline__ unsigned int cvtpk(float lo, float hi) {
    // 2 fp32 -> 2 bf16 (RNE), packed: lo -> bits[15:0], hi -> bits[31:16]
    unsigned int r;
    asm("v_cvt_pk_bf16_f32 %0, %1, %2" : "=v"(r) : "v"(lo), "v"(hi));
    return r;
}

__device__ __forceinline__ uint4 cvt8(float4 v0, float4 v1) {
    // 8 fp32 -> 8 bf16 (16 B)
    uint4 r;
    r.x = cvtpk(v0.x, v0.y);
    r.y = cvtpk(v0.z, v0.w);
    r.z = cvtpk(v1.x, v1.y);
    r.w = cvtpk(v1.z, v1.w);
    return r;
}

// Streaming fp32->bf16 for one segment: each thread owns `upt` units
// (1 unit = 8 fp32 = 32 B in, 16 B out), strided for coalescing.
// Fully unrolled so all loads of the batch are issued before the stores.
__device__ __forceinline__ void conv_seg(const float* __restrict__ src,
                                         unsigned short* __restrict__ dst,
                                         int unit0, int stride) {
    const float4* s4 = (const float4*)src;
    uint4*       d4 = (uint4*)dst;
    float4 v[16];
#pragma unroll
    for (int k = 0; k < 8; ++k) {
        int u = unit0 + k * stride;
        v[2 * k + 0] = s4[2 * u + 0];
        v[2 * k + 1] = s4[2 * u + 1];
    }
#pragma unroll
    for (int k = 0; k < 8; ++k) {
        int u = unit0 + k * stride;
        d4[u] = cvt8(v[2 * k + 0], v[2 * k + 1]);
    }
}

// ---------------- Kernel 1: prep = sort (last block) + fp32->bf16 cvt --------
// meta layout (int): [0..7]=cnt, [8..15]=off, [16..16+4096)=perm
__global__ __launch_bounds__(256)
void moe_prep(const float* __restrict__ inp_f,
              const int* __restrict__ gate,
              const float* __restrict__ weight_f,
              unsigned short* __restrict__ wsA,
              unsigned short* __restrict__ wsB,
              int* __restrict__ meta) {
    const int tid = threadIdx.x;
    const int bid = blockIdx.x;

    if (bid == PREP_BLKS - 1) {
        // ---------------- sort: one block, validated logic ----------------
        __shared__ int cnt[NUM_EXPERT];
        __shared__ int off[NUM_EXPERT];
        __shared__ int wsum[4];
        const int lane = tid & 63;
        const int wave = tid >> 6;

        int gv[16];
        const int4* gp = (const int4*)(gate + tid * 16);
#pragma unroll
        for (int i = 0; i < 4; ++i) {
            int4 v = gp[i];
            gv[i * 4 + 0] = v.x; gv[i * 4 + 1] = v.y;
            gv[i * 4 + 2] = v.z; gv[i * 4 + 3] = v.w;
        }
        int lc[NUM_EXPERT];
#pragma unroll
        for (int e = 0; e < NUM_EXPERT; ++e) {
            int c = 0;
#pragma unroll
            for (int j = 0; j < 16; ++j) c += (gv[j] == e) ? 1 : 0;
            lc[e] = c;
        }
        if (tid < NUM_EXPERT) cnt[tid] = 0;
        __syncthreads();
#pragma unroll
        for (int e = 0; e < NUM_EXPERT; ++e) {
            int c = lc[e];
#pragma unroll
            for (int d = 32; d > 0; d >>= 1) c += __shfl_down(c, d);
            if (lane == 0 && c) atomicAdd(&cnt[e], c);
        }
        __syncthreads();
        if (tid == 0) {
            int a = 0;
#pragma unroll
            for (int e = 0; e < NUM_EXPERT; ++e) { off[e] = a; a += cnt[e]; }
        }
        __syncthreads();
        if (tid < NUM_EXPERT) { meta[tid] = cnt[tid]; meta[8 + tid] = off[tid]; }

        int* perm = meta + 16;
#pragma unroll
        for (int e = 0; e < NUM_EXPERT; ++e) {
            int c_t = lc[e];
            int inc = c_t;
#pragma unroll
            for (int d = 1; d < 64; d <<= 1) {
                int t = __shfl_up(inc, d);
                if (lane >= d) inc += t;
            }
            if (lane == 63) wsum[wave] = inc;
            __syncthreads();
            int base = off[e];
#pragma unroll
            for (int w = 0; w < 4; ++w) if (w < wave) base += wsum[w];
            int rank = base + inc - c_t;
#pragma unroll
            for (int j = 0; j < 16; ++j) {
                if (gv[j] == e) { perm[rank] = tid * 16 + j; rank++; }
            }
            __syncthreads();
        }
    } else if (bid < CONV_BLKS_INP) {
        // inp: 4M floats = 512K units; 65536 threads x 8 units
        conv_seg(inp_f, wsA, bid * 256 + tid, CONV_BLKS_INP * 256);
    } else {
        // weight: 32M floats = 4M units; 524288 threads x 8 units
        conv_seg(weight_f, wsB, (bid - CONV_BLKS_INP) * 256 + tid,
                 CONV_BLKS_W * 256);
    }
}

// ---------------- Kernel 2: bf16 grouped GEMM, LDS = exactly 32 KB -----------
// C[tok][n] = sum_k inp[tok][k] * W[e][n][k]   (both operands K-contiguous)
// Proven R0 kernel: global_load_lds DMA staging, XOR-swizzled LDS, 5 blk/CU.
// NOTE: plain __launch_bounds__(256). A (256,5) min-waves hint forced VGPR
// 92->48 and spilled the accumulator to scratch (3.5x slower).
__global__ __launch_bounds__(256)
void moe_gemm_bf16(const unsigned short* __restrict__ inp,
                   const unsigned short* __restrict__ weight,
                   const int* __restrict__ meta,
                   float* __restrict__ out) {
    __shared__ __align__(16) unsigned short As[BM * BK];   // 16 KB
    __shared__ __align__(16) unsigned short Bs[BN * BK];   // 16 KB  (total 32768 B)

    const int* cnt  = meta;
    const int* off  = meta + 8;
    const int* perm = meta + 16;

    // ---- map blockIdx.y -> (expert, local row-tile); block-uniform ----
    int local = blockIdx.y;
    int e = -1, grp_cnt = 0, grp_off = 0;
#pragma unroll
    for (int i = 0; i < NUM_EXPERT; ++i) {
        int c = cnt[i];
        int t = (c + BM - 1) >> 7;
        if (e < 0) {
            if (local < t) { e = i; grp_cnt = c; grp_off = off[i]; }
            else           local -= t;
        }
    }
    if (e < 0) return;

    const int n0   = blockIdx.x * BN;
    const int row0 = local * BM;
    int vcnt = grp_cnt - row0; if (vcnt > BM) vcnt = BM;

    const int tid  = threadIdx.x;
    const int lane = tid & 63;
    const int wave = tid >> 6;

    // ---- staging descriptors: thread stages chunks c = i*256+tid (16 B each).
    // LDS slot (row=c>>3, kcp=c&7) receives global chunk kc = kcp ^ (row&7).
    const char* ag[4]; const char* bg[4];
    char* al[4]; char* bl[4];
    const char* inp_b = (const char*)inp;
    const char* w_b   = (const char*)weight + (size_t)e * (size_t)(OUT_FEAT * IN_FEAT) * 2;
#pragma unroll
    for (int i = 0; i < 4; ++i) {
        int c   = i * 256 + tid;
        int row = c >> 3;
        int kc  = (c & 7) ^ (row & 7);
        int p   = row0 + row; if (p > grp_cnt - 1) p = grp_cnt - 1;  // clamp tail
        int tok = perm[grp_off + p];
        ag[i] = inp_b + (size_t)tok * (IN_FEAT * 2) + kc * 16;
        bg[i] = w_b   + (size_t)(n0 + row) * (IN_FEAT * 2) + kc * 16;
        al[i] = (char*)As + c * 16;
        bl[i] = (char*)Bs + c * 16;
    }

    // ---- fragment LDS byte offsets: row*128 + ((ks*4+quad)^(row&7))*16 ----
    const int wm   = (wave & 1) * 64;
    const int wn   = (wave >> 1) * 64;
    const int lcol = lane & 15;
    const int quad = lane >> 4;

    int aoff[2][4], boff[2][4];
#pragma unroll
    for (int ks = 0; ks < 2; ++ks)
#pragma unroll
        for (int t = 0; t < 4; ++t) {
            int ra = wm + t * 16 + lcol;
            aoff[ks][t] = ra * 128 + (((ks * 4 + quad) ^ (ra & 7)) * 16);
            int rb = wn + t * 16 + lcol;
            boff[ks][t] = rb * 128 + (((ks * 4 + quad) ^ (rb & 7)) * 16);
        }

    const f32x4 vzero = {0.f, 0.f, 0.f, 0.f};
    f32x4 acc[4][4];
#pragma unroll
    for (int i = 0; i < 4; ++i)
#pragma unroll
        for (int j = 0; j < 4; ++j) acc[i][j] = vzero;

    const char* As_b = (const char*)As;
    const char* Bs_b = (const char*)Bs;

    for (int k0 = 0; k0 < IN_FEAT; k0 += BK) {
#pragma unroll
        for (int i = 0; i < 4; ++i) { async_cp16(ag[i], al[i]); ag[i] += BK * 2; }
#pragma unroll
        for (int i = 0; i < 4; ++i) { async_cp16(bg[i], bl[i]); bg[i] += BK * 2; }
        __builtin_amdgcn_s_waitcnt(0);   // drain global_load_lds before barrier
        __syncthreads();
#pragma unroll
        for (int ks = 0; ks < 2; ++ks) {
            short8 af[4], bf[4];
#pragma unroll
            for (int im = 0; im < 4; ++im) af[im] = *(const short8*)(As_b + aoff[ks][im]);
#pragma unroll
            for (int jn = 0; jn < 4; ++jn) bf[jn] = *(const short8*)(Bs_b + boff[ks][jn]);
#pragma unroll
            for (int im = 0; im < 4; ++im)
#pragma unroll
                for (int jn = 0; jn < 4; ++jn)
                    acc[im][jn] = __builtin_amdgcn_mfma_f32_16x16x32_bf16(
                        af[im], bf[jn], acc[im][jn], 0, 0, 0);
        }
        __syncthreads();
    }

    // ---- epilogue: C/D layout col=lane&15, row=quad*4+reg; fp32 scatter ----
#pragma unroll
    for (int im = 0; im < 4; ++im) {
#pragma unroll
        for (int reg = 0; reg < 4; ++reg) {
            int r = wm + im * 16 + quad * 4 + reg;
            if (r < vcnt) {
                int tok = perm[grp_off + row0 + r];
                float* orow = out + (size_t)tok * OUT_FEAT + (n0 + wn + lcol);
#pragma unroll
                for (int jn = 0; jn < 4; ++jn)
                    orow[jn * 16] = acc[im][jn][reg];
            }
        }
    }
}

extern "C" void kernel_launch(void* const* d_in, const int* in_sizes, int n_in,
                              void* d_out, int out_size, void* d_ws, size_t ws_size,
                              hipStream_t stream) {
    const float* inp    = (const float*)d_in[0];   // fp32 [4096,1024]
    const int*   gate   = (const int*)d_in[1];     // int32 [4096]
    const float* weight = (const float*)d_in[2];   // fp32 [8,4096,1024]
    float*       out    = (float*)d_out;           // fp32 [4096,4096]
    (void)in_sizes; (void)n_in; (void)out_size; (void)ws_size;

    const size_t n_inp = (size_t)N_TOKENS * IN_FEAT;                 // 4M elems
    const size_t n_w   = (size_t)NUM_EXPERT * OUT_FEAT * IN_FEAT;    // 32M elems

    unsigned short* wsA  = (unsigned short*)d_ws;        // 8 MB bf16 inp
    unsigned short* wsB  = wsA + n_inp;                  // 64 MB bf16 weight
    int*            meta = (int*)(wsB + n_w);            // cnt/off/perm (~16.5 KB)

    moe_prep<<<PREP_BLKS, 256, 0, stream>>>(inp, gate, weight, wsA, wsB, meta);
    dim3 grid(OUT_FEAT / BN, MAX_ROW_TILES);
    moe_gemm_bf16<<<grid, 256, 0, stream>>>(wsA, wsB, meta, out);
}

// Round 7
// 275.013 us; speedup vs baseline: 1.3987x; 1.0373x over previous
//
#include <hip/hip_runtime.h>
#include <stdint.h>

#define NUM_EXPERT 8
#define IN_FEAT 1024
#define OUT_FEAT 4096
#define N_TOKENS 4096

#define BM 128
#define BN 128
#define BK 64
#define MAX_ROW_TILES 40      // worst-case sum_e ceil(cnt_e/128)

// conv: 144 MB fp32 in 64-KB blocks; 256 blocks inp + 2048 weight; +1 sort
#define CONV_BLKS_INP 256
#define CONV_BLKS 2304
#define PREP_BLKS (CONV_BLKS + 1)   // 2305

typedef __attribute__((ext_vector_type(8))) short short8;   // 8 x bf16 bits
typedef __attribute__((ext_vector_type(4))) float f32x4;

__device__ __forceinline__ void async_cp16(const void* g, void* l) {
    __builtin_amdgcn_global_load_lds(
        (const __attribute__((address_space(1))) void*)g,
        (__attribute__((address_space(3))) void*)l, 16, 0, 0);
}

__device__ __forceinline__ unsigned int cvtpk(float lo, float hi) {
    // 2 fp32 -> 2 bf16 (RNE), packed: lo -> bits[15:0], hi -> bits[31:16]
    unsigned int r;
    asm("v_cvt_pk_bf16_f32 %0, %1, %2" : "=v"(r) : "v"(lo), "v"(hi));
    return r;
}

// ---------------- Kernel 1: prep = sort (last block) + fp32->bf16 cvt --------
// Converter: DMA-staged (global_load_lds -> LDS -> reg -> cvt -> store).
// Each wave owns a PRIVATE 16 KB LDS strip (no barriers): issue all 16x1KB
// DMA chunks up front, then drain with constant s_waitcnt vmcnt(15).
// Correctness of the constant wait: at drain step c, issued vmem ops =
// 16 cp + c stores; vmcnt(15) retires the oldest (16+c)-15 = c+1 ops,
// which in issue order are exactly cp_0..cp_c (stores are all newer).
// This keeps ~15 KB/wave of DMA in flight -> BW-limited, not latency-limited
// (the R5 reg-staged version compiled to VGPR=40, i.e. ~2-deep, 2.5 TB/s).
// meta layout (int): [0..7]=cnt, [8..15]=off, [16..16+4096)=perm
__global__ __launch_bounds__(256)
void moe_prep(const float* __restrict__ inp_f,
              const int* __restrict__ gate,
              const float* __restrict__ weight_f,
              unsigned short* __restrict__ wsA,
              unsigned short* __restrict__ wsB,
              int* __restrict__ meta) {
    const int tid = threadIdx.x;
    const int bid = blockIdx.x;

    if (bid == CONV_BLKS) {
        // ---------------- sort: one block, validated logic ----------------
        __shared__ int cnt[NUM_EXPERT];
        __shared__ int off[NUM_EXPERT];
        __shared__ int wsum[4];
        const int lane = tid & 63;
        const int wave = tid >> 6;

        int gv[16];
        const int4* gp = (const int4*)(gate + tid * 16);
#pragma unroll
        for (int i = 0; i < 4; ++i) {
            int4 v = gp[i];
            gv[i * 4 + 0] = v.x; gv[i * 4 + 1] = v.y;
            gv[i * 4 + 2] = v.z; gv[i * 4 + 3] = v.w;
        }
        int lc[NUM_EXPERT];
#pragma unroll
        for (int e = 0; e < NUM_EXPERT; ++e) {
            int c = 0;
#pragma unroll
            for (int j = 0; j < 16; ++j) c += (gv[j] == e) ? 1 : 0;
            lc[e] = c;
        }
        if (tid < NUM_EXPERT) cnt[tid] = 0;
        __syncthreads();
#pragma unroll
        for (int e = 0; e < NUM_EXPERT; ++e) {
            int c = lc[e];
#pragma unroll
            for (int d = 32; d > 0; d >>= 1) c += __shfl_down(c, d);
            if (lane == 0 && c) atomicAdd(&cnt[e], c);
        }
        __syncthreads();
        if (tid == 0) {
            int a = 0;
#pragma unroll
            for (int e = 0; e < NUM_EXPERT; ++e) { off[e] = a; a += cnt[e]; }
        }
        __syncthreads();
        if (tid < NUM_EXPERT) { meta[tid] = cnt[tid]; meta[8 + tid] = off[tid]; }

        int* perm = meta + 16;
#pragma unroll
        for (int e = 0; e < NUM_EXPERT; ++e) {
            int c_t = lc[e];
            int inc = c_t;
#pragma unroll
            for (int d = 1; d < 64; d <<= 1) {
                int t = __shfl_up(inc, d);
                if (lane >= d) inc += t;
            }
            if (lane == 63) wsum[wave] = inc;
            __syncthreads();
            int base = off[e];
#pragma unroll
            for (int w = 0; w < 4; ++w) if (w < wave) base += wsum[w];
            int rank = base + inc - c_t;
#pragma unroll
            for (int j = 0; j < 16; ++j) {
                if (gv[j] == e) { perm[rank] = tid * 16 + j; rank++; }
            }
            __syncthreads();
        }
    } else {
        // ---------------- DMA-staged converter: 64 KB in -> 32 KB out ----
        __shared__ __align__(16) char Ls[65536];   // 4 waves x 16 KB strips

        const char* src; char* dst;
        if (bid < CONV_BLKS_INP) {
            src = (const char*)inp_f    + (size_t)bid * 65536;
            dst = (char*)wsA            + (size_t)bid * 32768;
        } else {
            src = (const char*)weight_f + (size_t)(bid - CONV_BLKS_INP) * 65536;
            dst = (char*)wsB            + (size_t)(bid - CONV_BLKS_INP) * 32768;
        }

        const int wave = tid >> 6;
        const int lane = tid & 63;
        const char* gsrc  = src + wave * 16384 + lane * 16;  // per-lane global
        char*       strip = Ls  + wave * 16384;              // wave-uniform LDS

        // issue all 16 chunks (1 KB each at wave level); ~15 KB in flight
#pragma unroll
        for (int c = 0; c < 16; ++c)
            async_cp16(gsrc + c * 1024, strip + c * 1024);

        char* dw = dst + wave * 8192 + lane * 8;
#pragma unroll
        for (int c = 0; c < 16; ++c) {
            asm volatile("s_waitcnt vmcnt(15)" ::: "memory");
            __builtin_amdgcn_sched_barrier(0);
            float4 v = *(const float4*)(strip + c * 1024 + lane * 16);
            uint2 o;
            o.x = cvtpk(v.x, v.y);
            o.y = cvtpk(v.z, v.w);
            *(uint2*)(dw + c * 512) = o;
        }
    }
}

// ---------------- Kernel 2: bf16 grouped GEMM, LDS = exactly 32 KB -----------
// C[tok][n] = sum_k inp[tok][k] * W[e][n][k]   (both operands K-contiguous)
// Proven kernel: global_load_lds DMA staging, XOR-swizzled LDS, high residency.
// NOTE: plain __launch_bounds__(256). A (256,5) min-waves hint forced VGPR
// 92->48 and spilled the accumulator to scratch (3.5x slower).
__global__ __launch_bounds__(256)
void moe_gemm_bf16(const unsigned short* __restrict__ inp,
                   const unsigned short* __restrict__ weight,
                   const int* __restrict__ meta,
                   float* __restrict__ out) {
    __shared__ __align__(16) unsigned short As[BM * BK];   // 16 KB
    __shared__ __align__(16) unsigned short Bs[BN * BK];   // 16 KB  (total 32768 B)

    const int* cnt  = meta;
    const int* off  = meta + 8;
    const int* perm = meta + 16;

    // ---- map blockIdx.y -> (expert, local row-tile); block-uniform ----
    int local = blockIdx.y;
    int e = -1, grp_cnt = 0, grp_off = 0;
#pragma unroll
    for (int i = 0; i < NUM_EXPERT; ++i) {
        int c = cnt[i];
        int t = (c + BM - 1) >> 7;
        if (e < 0) {
            if (local < t) { e = i; grp_cnt = c; grp_off = off[i]; }
            else           local -= t;
        }
    }
    if (e < 0) return;

    const int n0   = blockIdx.x * BN;
    const int row0 = local * BM;
    int vcnt = grp_cnt - row0; if (vcnt > BM) vcnt = BM;

    const int tid  = threadIdx.x;
    const int lane = tid & 63;
    const int wave = tid >> 6;

    // ---- staging descriptors: thread stages chunks c = i*256+tid (16 B each).
    // LDS slot (row=c>>3, kcp=c&7) receives global chunk kc = kcp ^ (row&7).
    const char* ag[4]; const char* bg[4];
    char* al[4]; char* bl[4];
    const char* inp_b = (const char*)inp;
    const char* w_b   = (const char*)weight + (size_t)e * (size_t)(OUT_FEAT * IN_FEAT) * 2;
#pragma unroll
    for (int i = 0; i < 4; ++i) {
        int c   = i * 256 + tid;
        int row = c >> 3;
        int kc  = (c & 7) ^ (row & 7);
        int p   = row0 + row; if (p > grp_cnt - 1) p = grp_cnt - 1;  // clamp tail
        int tok = perm[grp_off + p];
        ag[i] = inp_b + (size_t)tok * (IN_FEAT * 2) + kc * 16;
        bg[i] = w_b   + (size_t)(n0 + row) * (IN_FEAT * 2) + kc * 16;
        al[i] = (char*)As + c * 16;
        bl[i] = (char*)Bs + c * 16;
    }

    // ---- fragment LDS byte offsets: row*128 + ((ks*4+quad)^(row&7))*16 ----
    const int wm   = (wave & 1) * 64;
    const int wn   = (wave >> 1) * 64;
    const int lcol = lane & 15;
    const int quad = lane >> 4;

    int aoff[2][4], boff[2][4];
#pragma unroll
    for (int ks = 0; ks < 2; ++ks)
#pragma unroll
        for (int t = 0; t < 4; ++t) {
            int ra = wm + t * 16 + lcol;
            aoff[ks][t] = ra * 128 + (((ks * 4 + quad) ^ (ra & 7)) * 16);
            int rb = wn + t * 16 + lcol;
            boff[ks][t] = rb * 128 + (((ks * 4 + quad) ^ (rb & 7)) * 16);
        }

    const f32x4 vzero = {0.f, 0.f, 0.f, 0.f};
    f32x4 acc[4][4];
#pragma unroll
    for (int i = 0; i < 4; ++i)
#pragma unroll
        for (int j = 0; j < 4; ++j) acc[i][j] = vzero;

    const char* As_b = (const char*)As;
    const char* Bs_b = (const char*)Bs;

    for (int k0 = 0; k0 < IN_FEAT; k0 += BK) {
#pragma unroll
        for (int i = 0; i < 4; ++i) { async_cp16(ag[i], al[i]); ag[i] += BK * 2; }
#pragma unroll
        for (int i = 0; i < 4; ++i) { async_cp16(bg[i], bl[i]); bg[i] += BK * 2; }
        __builtin_amdgcn_s_waitcnt(0);   // drain global_load_lds before barrier
        __syncthreads();
#pragma unroll
        for (int ks = 0; ks < 2; ++ks) {
            short8 af[4], bf[4];
#pragma unroll
            for (int im = 0; im < 4; ++im) af[im] = *(const short8*)(As_b + aoff[ks][im]);
#pragma unroll
            for (int jn = 0; jn < 4; ++jn) bf[jn] = *(const short8*)(Bs_b + boff[ks][jn]);
#pragma unroll
            for (int im = 0; im < 4; ++im)
#pragma unroll
                for (int jn = 0; jn < 4; ++jn)
                    acc[im][jn] = __builtin_amdgcn_mfma_f32_16x16x32_bf16(
                        af[im], bf[jn], acc[im][jn], 0, 0, 0);
        }
        __syncthreads();
    }

    // ---- epilogue: C/D layout col=lane&15, row=quad*4+reg; fp32 scatter ----
#pragma unroll
    for (int im = 0; im < 4; ++im) {
#pragma unroll
        for (int reg = 0; reg < 4; ++reg) {
            int r = wm + im * 16 + quad * 4 + reg;
            if (r < vcnt) {
                int tok = perm[grp_off + row0 + r];
                float* orow = out + (size_t)tok * OUT_FEAT + (n0 + wn + lcol);
#pragma unroll
                for (int jn = 0; jn < 4; ++jn)
                    orow[jn * 16] = acc[im][jn][reg];
            }
        }
    }
}

extern "C" void kernel_launch(void* const* d_in, const int* in_sizes, int n_in,
                              void* d_out, int out_size, void* d_ws, size_t ws_size,
                              hipStream_t stream) {
    const float* inp    = (const float*)d_in[0];   // fp32 [4096,1024]
    const int*   gate   = (const int*)d_in[1];     // int32 [4096]
    const float* weight = (const float*)d_in[2];   // fp32 [8,4096,1024]
    float*       out    = (float*)d_out;           // fp32 [4096,4096]
    (void)in_sizes; (void)n_in; (void)out_size; (void)ws_size;

    const size_t n_inp = (size_t)N_TOKENS * IN_FEAT;                 // 4M elems
    const size_t n_w   = (size_t)NUM_EXPERT * OUT_FEAT * IN_FEAT;    // 32M elems

    unsigned short* wsA  = (unsigned short*)d_ws;        // 8 MB bf16 inp
    unsigned short* wsB  = wsA + n_inp;                  // 64 MB bf16 weight
    int*            meta = (int*)(wsB + n_w);            // cnt/off/perm (~16.5 KB)

    moe_prep<<<PREP_BLKS, 256, 0, stream>>>(inp, gate, weight, wsA, wsB, meta);
    dim3 grid(OUT_FEAT / BN, MAX_ROW_TILES);
    moe_gemm_bf16<<<grid, 256, 0, stream>>>(wsA, wsB, meta, out);
}